// Round 1
// baseline (282.320 us; speedup 1.0000x reference)
//
#include <hip/hip_runtime.h>

typedef __bf16 bf16;
typedef __bf16 bf16x4 __attribute__((ext_vector_type(4)));
typedef __bf16 bf16x8 __attribute__((ext_vector_type(8)));
typedef float f32x4 __attribute__((ext_vector_type(4)));

#define B_ 128
#define T_ 200
#define V_ 50257
#define H_ 256
#define E_ 128
#define OOV_ 50
#define VO_ 50307          // V + OOV
#define NRG 64             // n-rows per score block
#define NTS 4              // 16-wide n-tiles per score block
#define GSC 786            // score blocks (786*64 = 50304 >= V)
#define PSTR 800           // pg_part row stride (one partial per block, padded)
#define GPJ 400            // proj blocks

__device__ __forceinline__ float sigmoid_(float x) { return 1.0f / (1.0f + __expf(-x)); }
__device__ __forceinline__ float tanh_(float x) { return 1.0f - 2.0f / (__expf(2.0f * x) + 1.0f); }

// K1: fused front kernel. blocks [0,128): pack Wc fp32 -> bf16 frag order
// [nt(16)][kstep(16)][lane(64)][8]; blocks [128,256): prep (hT, ginT).
__global__ void k_front(const float* Wc_w, bf16* WcPack,
                        const int* step_p, const float* enc, const float* prev,
                        const float* selread, const int* dec, const float* emb,
                        const float* Wi_w, const float* Wi_b,
                        float* hT, float* ginT) {
    if (blockIdx.x < 128) {
        int gid = blockIdx.x * 256 + threadIdx.x;   // 32768 float4s
        int n = gid >> 7;
        int k = (gid & 127) * 4;
        float4 v = *(const float4*)(Wc_w + n * 512 + k);
        int kstep = k >> 5, kin = k & 31;
        int q = kin >> 3, j0 = kin & 7;
        int r = n & 15, nt = n >> 4;
        int lane = q * 16 + r;
        bf16* d = WcPack + (((nt * 16 + kstep) * 64) + lane) * 8 + j0;
        d[0] = (bf16)v.x; d[1] = (bf16)v.y; d[2] = (bf16)v.z; d[3] = (bf16)v.w;
    } else {
        int b = blockIdx.x - 128, t = threadIdx.x;
        int step = step_p[0];
        float h;
        if (step == 0) {
            float acc = Wi_b[t];
            const float* er = enc + (b * T_ + (T_ - 1)) * 512;
            const float* wr = Wi_w + t * 512;
            for (int k = 0; k < 512; ++k) acc += er[k] * wr[k];
            h = acc;
        } else {
            h = prev[b * H_ + t];
        }
        hT[t * B_ + b] = h;
        for (int k = t; k < 512; k += 256)
            ginT[k * B_ + b] = (step == 0) ? 0.0f : selread[b * 512 + k];
        if (t < E_)
            ginT[(512 + t) * B_ + b] = emb[dec[b] * E_ + t];
    }
}

// K2: gi = gru_in @ W_ih^T + b_ih ; gh = h @ W_hh^T + b_hh
// K-split: 768 blocks, one output row each; threads (b, kh) with kh = K-half.
// Halves the serial MAC chain per thread and doubles resident waves vs the
// previous 384-block version (which ran at ~1.5 blocks/CU).
__global__ void k_gemm_gru(const float* W_ih, const float* b_ih,
                           const float* W_hh, const float* b_hh,
                           const float* ginT, const float* hT,
                           float* giT, float* ghT) {
    __shared__ float red[256];
    int rrow = blockIdx.x;            // 0..767
    int t = threadIdx.x;
    int b = t & 127, kh = t >> 7;
    const float* w = W_ih + rrow * 640 + kh * 320;
    const float* g = ginT + (kh * 320) * B_ + b;
    float a0 = 0.f, a1 = 0.f, a2 = 0.f, a3 = 0.f;
#pragma unroll 4
    for (int k = 0; k < 320; k += 4) {
        a0 += w[k]     * g[k * B_];
        a1 += w[k + 1] * g[(k + 1) * B_];
        a2 += w[k + 2] * g[(k + 2) * B_];
        a3 += w[k + 3] * g[(k + 3) * B_];
    }
    const float* w2 = W_hh + rrow * 256 + kh * 128;
    const float* hh = hT + (kh * 128) * B_ + b;
    float c0 = 0.f, c1 = 0.f, c2 = 0.f, c3 = 0.f;
#pragma unroll 4
    for (int k = 0; k < 128; k += 4) {
        c0 += w2[k]     * hh[k * B_];
        c1 += w2[k + 1] * hh[(k + 1) * B_];
        c2 += w2[k + 2] * hh[(k + 2) * B_];
        c3 += w2[k + 3] * hh[(k + 3) * B_];
    }
    red[t] = ((a0 + a1) + (a2 + a3));
    __syncthreads();
    if (kh == 0) giT[rrow * B_ + b] = b_ih[rrow] + red[b] + red[b + 128];
    __syncthreads();
    red[t] = ((c0 + c1) + (c2 + c3));
    __syncthreads();
    if (kh == 0) ghT[rrow * B_ + b] = b_hh[rrow] + red[b] + red[b + 128];
}

// K3: GRU cell -> decode_hidden fp32 (out) + bf16 A-fragment-packed copy
__global__ void k_gru_cell(const float* giT, const float* ghT, const float* hT,
                           float* out_dh, bf16* Apack) {
    int b = blockIdx.x, j = threadIdx.x;
    float ir = giT[j * B_ + b], iz = giT[(256 + j) * B_ + b], in_ = giT[(512 + j) * B_ + b];
    float hr = ghT[j * B_ + b], hz = ghT[(256 + j) * B_ + b], hn = ghT[(512 + j) * B_ + b];
    float hp = hT[j * B_ + b];
    float r = sigmoid_(ir + hr);
    float z = sigmoid_(iz + hz);
    float n = tanh_(in_ + r * hn);
    float h = (1.0f - z) * n + z * hp;
    out_dh[b * H_ + j] = h;
    // Apack[mt(8)][ks(8)][lane(64)][8]: m = mt*16 + (lane&15), k = ks*32 + (lane>>4)*8 + jj
    int mt = b >> 4, rr = b & 15, ks = j >> 5, q = (j >> 3) & 3, jj = j & 7;
    Apack[(((mt * 8 + ks) * 64) + (q * 16 + rr)) * 8 + jj] = (bf16)h;
}

// K4: merged MFMA kernel. blocks [0,GSC): score_g; blocks [GSC,GSC+GPJ): proj+score_c.
// LDS 34816 B -> 4 blocks/CU (was 43008 -> 3).
__global__ __launch_bounds__(256, 4) void k_mm(const bf16* Apack, const float* Wg_w,
                                               const float* Wg_b, const float* enc,
                                               const bf16* WcPack, const float* Wc_b,
                                               const float* dh, const int* idxs,
                                               float* out_prob, float* pg_part, float* expc) {
    __shared__ unsigned char smem[34816];
    int tid = threadIdx.x;
    int w = tid >> 6, lane = tid & 63;
    int r = lane & 15, q = lane >> 4;
    if (blockIdx.x < GSC) {
        // ---------------- score_g path ----------------
        int blk = blockIdx.x;
        int n0 = blk * NRG;
        bf16* Bs = (bf16*)smem;          // 64 rows x 256 k, stride 264
        // single-phase deep staging: 16 loads all in flight, then cvt+write
        float4 tmp[16];
#pragma unroll
        for (int j = 0; j < 16; ++j) {
            int f = j * 256 + tid;       // 4096 float4s
            int row = f >> 6, c4 = f & 63;
            int n = n0 + row;
            tmp[j] = (n < V_) ? *(const float4*)(Wg_w + n * 256 + c4 * 4)
                              : float4{0.f, 0.f, 0.f, 0.f};
        }
#pragma unroll
        for (int j = 0; j < 16; ++j) {
            int f = j * 256 + tid;
            int row = f >> 6, c4 = f & 63;
            bf16x4 o;
            o[0] = (bf16)tmp[j].x; o[1] = (bf16)tmp[j].y;
            o[2] = (bf16)tmp[j].z; o[3] = (bf16)tmp[j].w;
            *(bf16x4*)(Bs + row * 264 + c4 * 4) = o;
        }
        // A fragments loaded AFTER staging (registers free during staging)
        bf16x8 a[2][8];
#pragma unroll
        for (int p = 0; p < 2; ++p)
#pragma unroll
            for (int ks = 0; ks < 8; ++ks)
                a[p][ks] = *(const bf16x8*)(Apack + ((2 * w + p) * 8 + ks) * 512 + lane * 8);
        __syncthreads();
        f32x4 acc[8];
#pragma unroll
        for (int i = 0; i < 8; ++i) acc[i] = (f32x4){0.f, 0.f, 0.f, 0.f};
#pragma unroll
        for (int ks = 0; ks < 8; ++ks) {
#pragma unroll
            for (int nt = 0; nt < NTS; ++nt) {
                bf16x8 bfr = *(const bf16x8*)(Bs + (nt * 16 + r) * 264 + ks * 32 + q * 8);
                acc[nt * 2]     = __builtin_amdgcn_mfma_f32_16x16x32_bf16(a[0][ks], bfr, acc[nt * 2], 0, 0, 0);
                acc[nt * 2 + 1] = __builtin_amdgcn_mfma_f32_16x16x32_bf16(a[1][ks], bfr, acc[nt * 2 + 1], 0, 0, 0);
            }
        }
        __syncthreads();                 // Bs reads done; reuse smem as transpose buffer
        float* Tr = (float*)smem;        // 128 rows x 64, stride 68 (16B-aligned)
        float rsum[2][4];
#pragma unroll
        for (int p = 0; p < 2; ++p)
#pragma unroll
            for (int rg = 0; rg < 4; ++rg) rsum[p][rg] = 0.0f;
#pragma unroll
        for (int nt = 0; nt < NTS; ++nt) {
            int n = n0 + nt * 16 + r;
            bool valid = n < V_;
            float wgb = valid ? Wg_b[n] : 0.0f;
#pragma unroll
            for (int p = 0; p < 2; ++p) {
#pragma unroll
                for (int rg = 0; rg < 4; ++rg) {
                    int row = (2 * w + p) * 16 + q * 4 + rg;
                    float e = valid ? __expf(acc[nt * 2 + p][rg] + wgb) : 0.0f;
                    Tr[row * 68 + nt * 16 + r] = e;
                    rsum[p][rg] += e;    // in-register n-tile accumulation
                }
            }
        }
        // one short shfl chain per (p,rg): 32 cross-lane ops/wave (was 160)
#pragma unroll
        for (int p = 0; p < 2; ++p) {
#pragma unroll
            for (int rg = 0; rg < 4; ++rg) {
                float s = rsum[p][rg];
                s += __shfl_xor(s, 1);
                s += __shfl_xor(s, 2);
                s += __shfl_xor(s, 4);
                s += __shfl_xor(s, 8);
                if (r == 0) {
                    int row = (2 * w + p) * 16 + q * 4 + rg;
                    pg_part[row * PSTR + blk] = s;
                }
            }
        }
        __syncthreads();
        // coalesced stores: 256B-contiguous run per row (16 float4)
        if (blk < GSC - 1) {
#pragma unroll
            for (int rnd = 0; rnd < 8; ++rnd) {
                int f = rnd * 256 + tid;            // 2048 float4s
                int row = f >> 4;
                int c4 = f & 15;
                float4 v = *(const float4*)(Tr + row * 68 + c4 * 4);
                *(float4*)(out_prob + row * VO_ + n0 + c4 * 4) = v;
            }
        } else {
#pragma unroll
            for (int rnd = 0; rnd < 8; ++rnd) {
                int f = rnd * 256 + tid;
                int row = f >> 4;
                int c4 = f & 15;
#pragma unroll
                for (int i = 0; i < 4; ++i) {
                    int n = n0 + c4 * 4 + i;
                    if (n < V_) out_prob[row * VO_ + n] = Tr[row * 68 + c4 * 4 + i];
                }
            }
        }
    } else {
        // ---------------- proj + score_c path ----------------
        int pblk = blockIdx.x - GSC;
        int m0 = pblk * 64;
        bf16* As = (bf16*)smem;                    // 64 rows x 256 k, stride 264
        float* sred = (float*)(smem + 33792);      // 64 x 4
        f32x4 acc[16];
#pragma unroll
        for (int i = 0; i < 16; ++i) acc[i] = (f32x4){0.f, 0.f, 0.f, 0.f};
        for (int half = 0; half < 2; ++half) {
            __syncthreads();
            // single-phase deep staging: 16 loads in flight
            float4 tmp[16];
#pragma unroll
            for (int j = 0; j < 16; ++j) {
                int f = j * 256 + tid;
                int row = f >> 6, c4 = f & 63;
                tmp[j] = *(const float4*)(enc + (m0 + row) * 512 + half * 256 + c4 * 4);
            }
#pragma unroll
            for (int j = 0; j < 16; ++j) {
                int f = j * 256 + tid;
                int row = f >> 6, c4 = f & 63;
                bf16x4 o;
                o[0] = (bf16)tmp[j].x; o[1] = (bf16)tmp[j].y;
                o[2] = (bf16)tmp[j].z; o[3] = (bf16)tmp[j].w;
                *(bf16x4*)(As + row * 264 + c4 * 4) = o;
            }
            __syncthreads();
#pragma unroll
            for (int ks = 0; ks < 8; ++ks) {
                int kstep = half * 8 + ks;
                bf16x8 bfr[4];
#pragma unroll
                for (int ntl = 0; ntl < 4; ++ntl)
                    bfr[ntl] = *(const bf16x8*)(WcPack + (((w * 4 + ntl) * 16 + kstep) * 64 + lane) * 8);
#pragma unroll
                for (int mt = 0; mt < 4; ++mt) {
                    bf16x8 a = *(const bf16x8*)(As + (mt * 16 + r) * 264 + ks * 32 + q * 8);
#pragma unroll
                    for (int ntl = 0; ntl < 4; ++ntl)
                        acc[mt * 4 + ntl] = __builtin_amdgcn_mfma_f32_16x16x32_bf16(a, bfr[ntl], acc[mt * 4 + ntl], 0, 0, 0);
                }
            }
        }
#pragma unroll
        for (int mt = 0; mt < 4; ++mt) {
#pragma unroll
            for (int rg = 0; rg < 4; ++rg) {
                int rowl = mt * 16 + q * 4 + rg;
                int row = m0 + rowl;
                int b = row / T_;
                float s = 0.0f;
#pragma unroll
                for (int ntl = 0; ntl < 4; ++ntl) {
                    int n = (w * 4 + ntl) * 16 + r;
                    float pv = tanh_(acc[mt * 4 + ntl][rg] + Wc_b[n]);
                    s += pv * dh[b * H_ + n];
                }
                s += __shfl_xor(s, 1);
                s += __shfl_xor(s, 2);
                s += __shfl_xor(s, 4);
                s += __shfl_xor(s, 8);
                if (r == 0) sred[rowl * 4 + w] = s;
            }
        }
        __syncthreads();
        if (tid < 64) {
            float s = sred[tid * 4] + sred[tid * 4 + 1] + sred[tid * 4 + 2] + sred[tid * 4 + 3];
            int row = m0 + tid;
            int b = row / T_, t = row - b * T_;
            float sc = tanh_(s);
            if (idxs[b * T_ + t] == 0) sc -= 10000.0f;
            expc[row] = __expf(sc);
        }
    }
}

// K5: per-b: inv = 1/(sum pg_part + sum expc); scatter RAW expc into out_prob
// (k_norm scales afterwards); selective_read with normalized pc.
__global__ void k_red_scatter(const float* pg_part, const float* expc_, const int* idxs,
                              const int* dec, const float* enc, float* inv_out,
                              float* out_prob, float* out_sel) {
    __shared__ float red[256];
    __shared__ float cf[256];
    int b = blockIdx.x, t = threadIdx.x;
    float s = 0.0f;
    for (int i = t; i < GSC; i += 256) s += pg_part[b * PSTR + i];
    if (t < T_) s += expc_[b * T_ + t];
    red[t] = s;
    __syncthreads();
    for (int k = 128; k > 0; k >>= 1) {
        if (t < k) red[t] += red[t + k];
        __syncthreads();
    }
    float iv = 1.0f / red[0];
    if (t == 0) inv_out[b] = iv;
    __syncthreads();
    int d = dec[b];
    float ec = 0.0f;
    int m = 0;
    if (t < T_) {
        int ix = idxs[b * T_ + t];
        ec = expc_[b * T_ + t];
        atomicAdd(&out_prob[b * VO_ + ix], ec);   // raw; k_norm multiplies by inv
        m = (ix == d) ? 1 : 0;
    }
    cf[t] = m ? ec * iv : 0.0f;
    red[t] = m ? 1.0f : 0.0f;
    __syncthreads();
    for (int k = 128; k > 0; k >>= 1) {
        if (t < k) red[t] += red[t + k];
        __syncthreads();
    }
    float tot = red[0];
    float scale = (tot > 1.0f) ? 1.0f / tot : 1.0f;
    float a0 = 0.0f, a1 = 0.0f;
    for (int tt = 0; tt < T_; ++tt) {
        float c = cf[tt];
        if (c != 0.0f) {
            float wgt = c * scale;
            a0 += wgt * enc[(b * T_ + tt) * 512 + t];
            a1 += wgt * enc[(b * T_ + tt) * 512 + t + 256];
        }
    }
    out_sel[b * 512 + t] = a0;
    out_sel[b * 512 + t + 256] = a1;
}

// K6: normalize out_prob in place (x inv), fill OOV pad with 1e-4
__global__ void k_norm(float* out_prob, const float* inv) {
    int i4 = blockIdx.x * 256 + threadIdx.x;
    if (i4 >= (B_ * VO_ / 4)) return;
    float4 vv = ((const float4*)out_prob)[i4];
    float r[4];
    int base = i4 * 4;
#pragma unroll
    for (int c = 0; c < 4; ++c) {
        int idx = base + c;
        int b = idx / VO_;
        int v = idx - b * VO_;
        float x = (c == 0) ? vv.x : (c == 1) ? vv.y : (c == 2) ? vv.z : vv.w;
        r[c] = (v < V_) ? x * inv[b] : 1e-4f;
    }
    ((float4*)out_prob)[i4] = make_float4(r[0], r[1], r[2], r[3]);
}

extern "C" void kernel_launch(void* const* d_in, const int* in_sizes, int n_in,
                              void* d_out, int out_size, void* d_ws, size_t ws_size,
                              hipStream_t stream) {
    const int*   dec     = (const int*)d_in[0];
    const float* enc     = (const float*)d_in[1];
    const int*   idxs    = (const int*)d_in[2];
    const float* prev    = (const float*)d_in[3];
    const float* selread = (const float*)d_in[4];
    const int*   step_p  = (const int*)d_in[5];
    const float* emb     = (const float*)d_in[6];
    const float* W_ih    = (const float*)d_in[7];
    const float* W_hh    = (const float*)d_in[8];
    const float* b_ih    = (const float*)d_in[9];
    const float* b_hh    = (const float*)d_in[10];
    const float* Wi_w    = (const float*)d_in[11];
    const float* Wi_b    = (const float*)d_in[12];
    const float* Wg_w    = (const float*)d_in[13];
    const float* Wg_b    = (const float*)d_in[14];
    const float* Wc_w    = (const float*)d_in[15];
    const float* Wc_b    = (const float*)d_in[16];

    float* ws     = (float*)d_ws;
    float* hT     = ws;                 // 32768
    float* ginT   = ws + 32768;         // 81920
    float* giT    = ws + 114688;        // 98304
    float* ghT    = ws + 212992;        // 98304
    float* inv    = ws + 311296;        // 128
    float* expc   = ws + 311552;        // 25600
    float* pgp    = ws + 337152;        // 128*800 = 102400
    bf16*  Apack  = (bf16*)(ws + 741376);   // 32768 bf16 (64KB)
    bf16*  WcPack = (bf16*)(ws + 757760);   // 131072 bf16 (256KB)

    float* out      = (float*)d_out;
    float* out_prob = out;                       // 128*50307
    float* out_dh   = out + 6439296;             // 128*256
    float* out_sel  = out + 6439296 + 32768;     // 128*512

    k_front<<<256, 256, 0, stream>>>(Wc_w, WcPack, step_p, enc, prev, selread, dec,
                                     emb, Wi_w, Wi_b, hT, ginT);
    k_gemm_gru<<<768, 256, 0, stream>>>(W_ih, b_ih, W_hh, b_hh, ginT, hT, giT, ghT);
    k_gru_cell<<<B_, 256, 0, stream>>>(giT, ghT, hT, out_dh, Apack);
    k_mm<<<GSC + GPJ, 256, 0, stream>>>(Apack, Wg_w, Wg_b, enc, WcPack, Wc_b,
                                        out_dh, idxs, out_prob, pgp, expc);
    k_red_scatter<<<B_, 256, 0, stream>>>(pgp, expc, idxs, dec, enc, inv, out_prob, out_sel);
    k_norm<<<(B_ * VO_ / 4 + 255) / 256, 256, 0, stream>>>(out_prob, inv);
}

// Round 3
// 279.603 us; speedup vs baseline: 1.0097x; 1.0097x over previous
//
#include <hip/hip_runtime.h>

typedef __bf16 bf16;
typedef __bf16 bf16x4 __attribute__((ext_vector_type(4)));
typedef __bf16 bf16x8 __attribute__((ext_vector_type(8)));
typedef float f32x4 __attribute__((ext_vector_type(4)));

#define B_ 128
#define T_ 200
#define V_ 50257
#define H_ 256
#define E_ 128
#define OOV_ 50
#define VO_ 50307          // V + OOV
#define NRG 80             // n-rows per score block
#define NTS 5              // 16-wide n-tiles per score block
#define GSC 629            // score blocks (629*80 = 50320 >= V)
#define PSTR 640           // pg_part row stride (one partial per block, padded)
#define GPJ 400            // proj blocks

__device__ __forceinline__ float sigmoid_(float x) { return 1.0f / (1.0f + __expf(-x)); }
__device__ __forceinline__ float tanh_(float x) { return 1.0f - 2.0f / (__expf(2.0f * x) + 1.0f); }

// K1: fused front kernel. blocks [0,128): pack Wc fp32 -> bf16 frag order
// [nt(16)][kstep(16)][lane(64)][8]; blocks [128,256): prep (hT, ginT).
__global__ void k_front(const float* Wc_w, bf16* WcPack,
                        const int* step_p, const float* enc, const float* prev,
                        const float* selread, const int* dec, const float* emb,
                        const float* Wi_w, const float* Wi_b,
                        float* hT, float* ginT) {
    if (blockIdx.x < 128) {
        int gid = blockIdx.x * 256 + threadIdx.x;   // 32768 float4s
        int n = gid >> 7;
        int k = (gid & 127) * 4;
        float4 v = *(const float4*)(Wc_w + n * 512 + k);
        int kstep = k >> 5, kin = k & 31;
        int q = kin >> 3, j0 = kin & 7;
        int r = n & 15, nt = n >> 4;
        int lane = q * 16 + r;
        bf16* d = WcPack + (((nt * 16 + kstep) * 64) + lane) * 8 + j0;
        d[0] = (bf16)v.x; d[1] = (bf16)v.y; d[2] = (bf16)v.z; d[3] = (bf16)v.w;
    } else {
        int b = blockIdx.x - 128, t = threadIdx.x;
        int step = step_p[0];
        float h;
        if (step == 0) {
            float acc = Wi_b[t];
            const float* er = enc + (b * T_ + (T_ - 1)) * 512;
            const float* wr = Wi_w + t * 512;
            for (int k = 0; k < 512; ++k) acc += er[k] * wr[k];
            h = acc;
        } else {
            h = prev[b * H_ + t];
        }
        hT[t * B_ + b] = h;
        for (int k = t; k < 512; k += 256)
            ginT[k * B_ + b] = (step == 0) ? 0.0f : selread[b * 512 + k];
        if (t < E_)
            ginT[(512 + t) * B_ + b] = emb[dec[b] * E_ + t];
    }
}

// K2: gi = gru_in @ W_ih^T + b_ih ; gh = h @ W_hh^T + b_hh  (K-split, 768 blocks)
__global__ void k_gemm_gru(const float* W_ih, const float* b_ih,
                           const float* W_hh, const float* b_hh,
                           const float* ginT, const float* hT,
                           float* giT, float* ghT) {
    __shared__ float red[256];
    int rrow = blockIdx.x;            // 0..767
    int t = threadIdx.x;
    int b = t & 127, kh = t >> 7;
    const float* w = W_ih + rrow * 640 + kh * 320;
    const float* g = ginT + (kh * 320) * B_ + b;
    float a0 = 0.f, a1 = 0.f, a2 = 0.f, a3 = 0.f;
#pragma unroll 4
    for (int k = 0; k < 320; k += 4) {
        a0 += w[k]     * g[k * B_];
        a1 += w[k + 1] * g[(k + 1) * B_];
        a2 += w[k + 2] * g[(k + 2) * B_];
        a3 += w[k + 3] * g[(k + 3) * B_];
    }
    const float* w2 = W_hh + rrow * 256 + kh * 128;
    const float* hh = hT + (kh * 128) * B_ + b;
    float c0 = 0.f, c1 = 0.f, c2 = 0.f, c3 = 0.f;
#pragma unroll 4
    for (int k = 0; k < 128; k += 4) {
        c0 += w2[k]     * hh[k * B_];
        c1 += w2[k + 1] * hh[(k + 1) * B_];
        c2 += w2[k + 2] * hh[(k + 2) * B_];
        c3 += w2[k + 3] * hh[(k + 3) * B_];
    }
    red[t] = ((a0 + a1) + (a2 + a3));
    __syncthreads();
    if (kh == 0) giT[rrow * B_ + b] = b_ih[rrow] + red[b] + red[b + 128];
    __syncthreads();
    red[t] = ((c0 + c1) + (c2 + c3));
    __syncthreads();
    if (kh == 0) ghT[rrow * B_ + b] = b_hh[rrow] + red[b] + red[b + 128];
}

// K3: GRU cell -> decode_hidden fp32 (out) + bf16 A-fragment-packed copy
__global__ void k_gru_cell(const float* giT, const float* ghT, const float* hT,
                           float* out_dh, bf16* Apack) {
    int b = blockIdx.x, j = threadIdx.x;
    float ir = giT[j * B_ + b], iz = giT[(256 + j) * B_ + b], in_ = giT[(512 + j) * B_ + b];
    float hr = ghT[j * B_ + b], hz = ghT[(256 + j) * B_ + b], hn = ghT[(512 + j) * B_ + b];
    float hp = hT[j * B_ + b];
    float r = sigmoid_(ir + hr);
    float z = sigmoid_(iz + hz);
    float n = tanh_(in_ + r * hn);
    float h = (1.0f - z) * n + z * hp;
    out_dh[b * H_ + j] = h;
    // Apack[mt(8)][ks(8)][lane(64)][8]: m = mt*16 + (lane&15), k = ks*32 + (lane>>4)*8 + jj
    int mt = b >> 4, rr = b & 15, ks = j >> 5, q = (j >> 3) & 3, jj = j & 7;
    Apack[(((mt * 8 + ks) * 64) + (q * 16 + rr)) * 8 + jj] = (bf16)h;
}

// K4: merged MFMA kernel. blocks [0,GSC): score_g; blocks [GSC,GSC+GPJ): proj+score_c.
// Score path: NO LDS, no barriers — B-fragments read directly global->reg (Wg_w is
// single-use, staging it was pure overhead), C written straight from fragment layout.
__global__ __launch_bounds__(256, 3) void k_mm(const bf16* Apack, const float* Wg_w,
                                               const float* Wg_b, const float* enc,
                                               const bf16* WcPack, const float* Wc_b,
                                               const float* dh, const int* idxs,
                                               float* out_prob, float* pg_part, float* expc) {
    __shared__ unsigned char smem[34816];
    int tid = threadIdx.x;
    int w = tid >> 6, lane = tid & 63;
    int r = lane & 15, q = lane >> 4;
    if (blockIdx.x < GSC) {
        // ---------------- score_g path (LDS-free) ----------------
        int blk = blockIdx.x;
        int n0 = blk * NRG;
        // per-lane row pointers, clamped for the tail block
        const float* rp[NTS];
        bool valid[NTS];
        int nrow[NTS];
#pragma unroll
        for (int nt = 0; nt < NTS; ++nt) {
            int n = n0 + nt * 16 + r;
            valid[nt] = (n < V_);
            nrow[nt] = valid[nt] ? n : (V_ - 1);
            rp[nt] = Wg_w + nrow[nt] * 256 + q * 8;
        }
        f32x4 acc[10];
#pragma unroll
        for (int i = 0; i < 10; ++i) acc[i] = (f32x4){0.f, 0.f, 0.f, 0.f};
        // 1-deep pipeline over ks, but bf16-convert current step BEFORE issuing
        // next-step loads: live set = 10 bf16x8 frags + 10 in-flight float4 pairs
        float4 vA[NTS], vB[NTS];
#pragma unroll
        for (int nt = 0; nt < NTS; ++nt) {
            vA[nt] = *(const float4*)(rp[nt]);
            vB[nt] = *(const float4*)(rp[nt] + 4);
        }
#pragma unroll
        for (int ks = 0; ks < 8; ++ks) {
            // convert current step to bf16 fragments (frees vA/vB for reuse)
            bf16x8 bfr[NTS];
#pragma unroll
            for (int nt = 0; nt < NTS; ++nt) {
                float4 va = vA[nt], vb = vB[nt];
                bfr[nt][0] = (bf16)va.x; bfr[nt][1] = (bf16)va.y;
                bfr[nt][2] = (bf16)va.z; bfr[nt][3] = (bf16)va.w;
                bfr[nt][4] = (bf16)vb.x; bfr[nt][5] = (bf16)vb.y;
                bfr[nt][6] = (bf16)vb.z; bfr[nt][7] = (bf16)vb.w;
            }
            // issue next-step loads (overlap with MFMAs below)
            if (ks < 7) {
#pragma unroll
                for (int nt = 0; nt < NTS; ++nt) {
                    vA[nt] = *(const float4*)(rp[nt] + (ks + 1) * 32);
                    vB[nt] = *(const float4*)(rp[nt] + (ks + 1) * 32 + 4);
                }
            }
            bf16x8 a0 = *(const bf16x8*)(Apack + ((2 * w + 0) * 8 + ks) * 512 + lane * 8);
            bf16x8 a1 = *(const bf16x8*)(Apack + ((2 * w + 1) * 8 + ks) * 512 + lane * 8);
#pragma unroll
            for (int nt = 0; nt < NTS; ++nt) {
                acc[nt * 2]     = __builtin_amdgcn_mfma_f32_16x16x32_bf16(a0, bfr[nt], acc[nt * 2], 0, 0, 0);
                acc[nt * 2 + 1] = __builtin_amdgcn_mfma_f32_16x16x32_bf16(a1, bfr[nt], acc[nt * 2 + 1], 0, 0, 0);
            }
        }
        // epilogue: exp, direct fragment-layout stores (16-lane groups write 64B runs),
        // in-register row sums + one short shfl chain per (p,rg)
        float rsum[2][4];
#pragma unroll
        for (int p = 0; p < 2; ++p)
#pragma unroll
            for (int rg = 0; rg < 4; ++rg) rsum[p][rg] = 0.0f;
#pragma unroll
        for (int nt = 0; nt < NTS; ++nt) {
            float wgb = Wg_b[nrow[nt]];
            int n = n0 + nt * 16 + r;
#pragma unroll
            for (int p = 0; p < 2; ++p) {
#pragma unroll
                for (int rg = 0; rg < 4; ++rg) {
                    int row = (2 * w + p) * 16 + q * 4 + rg;
                    float e = valid[nt] ? __expf(acc[nt * 2 + p][rg] + wgb) : 0.0f;
                    rsum[p][rg] += e;
                    if (valid[nt]) out_prob[row * VO_ + n] = e;
                }
            }
        }
#pragma unroll
        for (int p = 0; p < 2; ++p) {
#pragma unroll
            for (int rg = 0; rg < 4; ++rg) {
                float s = rsum[p][rg];
                s += __shfl_xor(s, 1);
                s += __shfl_xor(s, 2);
                s += __shfl_xor(s, 4);
                s += __shfl_xor(s, 8);
                if (r == 0) {
                    int row = (2 * w + p) * 16 + q * 4 + rg;
                    pg_part[row * PSTR + blk] = s;
                }
            }
        }
    } else {
        // ---------------- proj + score_c path ----------------
        int pblk = blockIdx.x - GSC;
        int m0 = pblk * 64;
        bf16* As = (bf16*)smem;                    // 64 rows x 256 k, stride 264
        float* sred = (float*)(smem + 33792);      // 64 x 4
        f32x4 acc[16];
#pragma unroll
        for (int i = 0; i < 16; ++i) acc[i] = (f32x4){0.f, 0.f, 0.f, 0.f};
        for (int half = 0; half < 2; ++half) {
            __syncthreads();
            // two-phase staging: 16 rounds = 2 x (8 loads, 8 cvt+write)
#pragma unroll
            for (int ph = 0; ph < 2; ++ph) {
                float4 tmp[8];
#pragma unroll
                for (int j = 0; j < 8; ++j) {
                    int f = (ph * 8 + j) * 256 + tid;
                    int row = f >> 6, c4 = f & 63;
                    tmp[j] = *(const float4*)(enc + (m0 + row) * 512 + half * 256 + c4 * 4);
                }
#pragma unroll
                for (int j = 0; j < 8; ++j) {
                    int f = (ph * 8 + j) * 256 + tid;
                    int row = f >> 6, c4 = f & 63;
                    bf16x4 o;
                    o[0] = (bf16)tmp[j].x; o[1] = (bf16)tmp[j].y;
                    o[2] = (bf16)tmp[j].z; o[3] = (bf16)tmp[j].w;
                    *(bf16x4*)(As + row * 264 + c4 * 4) = o;
                }
            }
            __syncthreads();
#pragma unroll
            for (int ks = 0; ks < 8; ++ks) {
                int kstep = half * 8 + ks;
                bf16x8 bfr[4];
#pragma unroll
                for (int ntl = 0; ntl < 4; ++ntl)
                    bfr[ntl] = *(const bf16x8*)(WcPack + (((w * 4 + ntl) * 16 + kstep) * 64 + lane) * 8);
#pragma unroll
                for (int mt = 0; mt < 4; ++mt) {
                    bf16x8 a = *(const bf16x8*)(As + (mt * 16 + r) * 264 + ks * 32 + q * 8);
#pragma unroll
                    for (int ntl = 0; ntl < 4; ++ntl)
                        acc[mt * 4 + ntl] = __builtin_amdgcn_mfma_f32_16x16x32_bf16(a, bfr[ntl], acc[mt * 4 + ntl], 0, 0, 0);
                }
            }
        }
#pragma unroll
        for (int mt = 0; mt < 4; ++mt) {
#pragma unroll
            for (int rg = 0; rg < 4; ++rg) {
                int rowl = mt * 16 + q * 4 + rg;
                int row = m0 + rowl;
                int b = row / T_;
                float s = 0.0f;
#pragma unroll
                for (int ntl = 0; ntl < 4; ++ntl) {
                    int n = (w * 4 + ntl) * 16 + r;
                    float pv = tanh_(acc[mt * 4 + ntl][rg] + Wc_b[n]);
                    s += pv * dh[b * H_ + n];
                }
                s += __shfl_xor(s, 1);
                s += __shfl_xor(s, 2);
                s += __shfl_xor(s, 4);
                s += __shfl_xor(s, 8);
                if (r == 0) sred[rowl * 4 + w] = s;
            }
        }
        __syncthreads();
        if (tid < 64) {
            float s = sred[tid * 4] + sred[tid * 4 + 1] + sred[tid * 4 + 2] + sred[tid * 4 + 3];
            int row = m0 + tid;
            int b = row / T_, t = row - b * T_;
            float sc = tanh_(s);
            if (idxs[b * T_ + t] == 0) sc -= 10000.0f;
            expc[row] = __expf(sc);
        }
    }
}

// K5: fused reduce + scatter + normalize + selective_read.
// 2 blocks per batch row b (hf = column half). Each block: computes inv (redundant,
// cheap), scatters expc ONLY into its own column half (disjoint -> no cross-block
// race), computes its 256 dims of selective_read, then normalizes its half of
// out_prob row b in place (k_norm eliminated).
__global__ void k_red_scatter(const float* pg_part, const float* expc_, const int* idxs,
                              const int* dec, const float* enc,
                              float* out_prob, float* out_sel) {
    __shared__ float red[256];
    __shared__ float cf[256];
    int b = blockIdx.x >> 1, hf = blockIdx.x & 1;
    int t = threadIdx.x;
    float s = 0.0f;
    for (int i = t; i < GSC; i += 256) s += pg_part[b * PSTR + i];
    if (t < T_) s += expc_[b * T_ + t];
    red[t] = s;
    __syncthreads();
    for (int k = 128; k > 0; k >>= 1) {
        if (t < k) red[t] += red[t + k];
        __syncthreads();
    }
    float iv = 1.0f / red[0];
    __syncthreads();
    int d = dec[b];
    const int halfc = (VO_ + 1) / 2;          // 25154
    int cl0 = hf * halfc;
    int cl1 = (cl0 + halfc < VO_) ? cl0 + halfc : VO_;
    float ec = 0.0f;
    int m = 0;
    if (t < T_) {
        int ix = idxs[b * T_ + t];
        ec = expc_[b * T_ + t];
        if (ix >= cl0 && ix < cl1)
            atomicAdd(&out_prob[b * VO_ + ix], ec);   // raw; normalized below
        m = (ix == d) ? 1 : 0;
    }
    cf[t] = m ? ec * iv : 0.0f;
    red[t] = m ? 1.0f : 0.0f;
    __syncthreads();
    for (int k = 128; k > 0; k >>= 1) {
        if (t < k) red[t] += red[t + k];
        __syncthreads();
    }
    float tot = red[0];
    float scale = (tot > 1.0f) ? 1.0f / tot : 1.0f;
    // selective_read: this block covers dim = t + hf*256
    int dim = t + hf * 256;
    float a0 = 0.0f;
    for (int tt = 0; tt < T_; ++tt) {
        float c = cf[tt];
        if (c != 0.0f) a0 += c * scale * enc[(b * T_ + tt) * 512 + dim];
    }
    out_sel[b * 512 + dim] = a0;
    // normalize own column half of row b (scatters to this half came only from
    // this block; fence + sync makes them visible)
    __threadfence();
    __syncthreads();
    int base = b * VO_;
    int s0 = base + cl0, s1 = base + cl1;
    int a4 = (s0 + 3) & ~3;
    int b4 = s1 & ~3;
    if (t < a4 - s0) {
        int i = s0 + t;
        int col = i - base;
        out_prob[i] = (col < V_) ? out_prob[i] * iv : 1e-4f;
    }
    if (t < s1 - b4) {
        int i = b4 + t;
        int col = i - base;
        out_prob[i] = (col < V_) ? out_prob[i] * iv : 1e-4f;
    }
    for (int i4 = a4 / 4 + t; i4 < b4 / 4; i4 += 256) {
        float4 v = *(const float4*)(out_prob + i4 * 4);
        int c0 = i4 * 4 - base;
        float o[4];
        o[0] = (c0 + 0 < V_) ? v.x * iv : 1e-4f;
        o[1] = (c0 + 1 < V_) ? v.y * iv : 1e-4f;
        o[2] = (c0 + 2 < V_) ? v.z * iv : 1e-4f;
        o[3] = (c0 + 3 < V_) ? v.w * iv : 1e-4f;
        *(float4*)(out_prob + i4 * 4) = make_float4(o[0], o[1], o[2], o[3]);
    }
}

extern "C" void kernel_launch(void* const* d_in, const int* in_sizes, int n_in,
                              void* d_out, int out_size, void* d_ws, size_t ws_size,
                              hipStream_t stream) {
    const int*   dec     = (const int*)d_in[0];
    const float* enc     = (const float*)d_in[1];
    const int*   idxs    = (const int*)d_in[2];
    const float* prev    = (const float*)d_in[3];
    const float* selread = (const float*)d_in[4];
    const int*   step_p  = (const int*)d_in[5];
    const float* emb     = (const float*)d_in[6];
    const float* W_ih    = (const float*)d_in[7];
    const float* W_hh    = (const float*)d_in[8];
    const float* b_ih    = (const float*)d_in[9];
    const float* b_hh    = (const float*)d_in[10];
    const float* Wi_w    = (const float*)d_in[11];
    const float* Wi_b    = (const float*)d_in[12];
    const float* Wg_w    = (const float*)d_in[13];
    const float* Wg_b    = (const float*)d_in[14];
    const float* Wc_w    = (const float*)d_in[15];
    const float* Wc_b    = (const float*)d_in[16];

    float* ws     = (float*)d_ws;
    float* hT     = ws;                 // 32768
    float* ginT   = ws + 32768;         // 81920
    float* giT    = ws + 114688;        // 98304
    float* ghT    = ws + 212992;        // 98304
    float* expc   = ws + 311552;        // 25600
    float* pgp    = ws + 337152;        // 128*640 = 81920
    bf16*  Apack  = (bf16*)(ws + 741376);   // 32768 bf16 (64KB)
    bf16*  WcPack = (bf16*)(ws + 757760);   // 131072 bf16 (256KB)

    float* out      = (float*)d_out;
    float* out_prob = out;                       // 128*50307
    float* out_dh   = out + 6439296;             // 128*256
    float* out_sel  = out + 6439296 + 32768;     // 128*512

    k_front<<<256, 256, 0, stream>>>(Wc_w, WcPack, step_p, enc, prev, selread, dec,
                                     emb, Wi_w, Wi_b, hT, ginT);
    k_gemm_gru<<<768, 256, 0, stream>>>(W_ih, b_ih, W_hh, b_hh, ginT, hT, giT, ghT);
    k_gru_cell<<<B_, 256, 0, stream>>>(giT, ghT, hT, out_dh, Apack);
    k_mm<<<GSC + GPJ, 256, 0, stream>>>(Apack, Wg_w, Wg_b, enc, WcPack, Wc_b,
                                        out_dh, idxs, out_prob, pgp, expc);
    k_red_scatter<<<256, 256, 0, stream>>>(pgp, expc, idxs, dec, enc, out_prob, out_sel);
}